// Round 1
// baseline (768.809 us; speedup 1.0000x reference)
//
#include <hip/hip_runtime.h>
#include <math.h>

// ---------------------------------------------------------------------------
// QuadraLayer fused implementation, bf16-MFMA path.
// Stage A: pack_w       - repack fp32 weights into MFMA B-fragment order (bf16)
// Stage B: k_mlp_ln     - x_proj = LN1(x + MLP1(x)), per-row, 64-row blocks
// Stage C: k_buffer     - K/V for t<15 only + router proj + banded attn1 -> buffer
// Stage D: k_attn_mlp   - q-proj + attn2(10 keys) + MLP2 + LN2 + LN3 -> out
// Layouts stay native [B,T,L,D]; attention kernels index (b,l,t) explicitly.
// ---------------------------------------------------------------------------

typedef short short8 __attribute__((ext_vector_type(8)));
typedef short short4v __attribute__((ext_vector_type(4)));
typedef float floatx4 __attribute__((ext_vector_type(4)));

#define MFMA_BF16(a, b, c) __builtin_amdgcn_mfma_f32_16x16x32_bf16((a), (b), (c), 0, 0, 0)

// f32 -> bf16 bits, round-to-nearest-even
__device__ __forceinline__ short f2b(float f) {
  unsigned u = __builtin_bit_cast(unsigned, f);
  u += 0x7FFFu + ((u >> 16) & 1u);
  return (short)(u >> 16);
}

__device__ __forceinline__ float gelu_exact(float v) {
  return 0.5f * v * (1.0f + erff(v * 0.70710678118654752f));
}

// ---------------------------------------------------------------------------
// Pack W[K,N] (row-major fp32) into bf16 B-fragments for mfma_f32_16x16x32_bf16.
// B-frag layout: lane holds B[k = kstep*32 + (lane>>4)*8 + j][n = ntile*16 + (lane&15)]
// packed[((nt*KS + ks)*64 + lane)*8 + j]
// ---------------------------------------------------------------------------
__global__ void pack_w(const float* __restrict__ W, short* __restrict__ P,
                       int KS, int N, int total) {
  int idx = blockIdx.x * 256 + threadIdx.x;
  if (idx >= total) return;
  int j    = idx & 7;
  int lane = (idx >> 3) & 63;
  int ks   = (idx >> 9) % KS;
  int nt   = idx / (KS << 9);
  int k = ks * 32 + ((lane >> 4) << 3) + j;
  int n = nt * 16 + (lane & 15);
  P[idx] = f2b(W[k * N + n]);
}

// ---------------------------------------------------------------------------
// Stage B: x_proj = LN(x + (gelu(x@W1+b1))@W2 + b2)  over 131072 rows of 128.
// 64 rows/block, 4 waves, each wave owns 16 rows. h (512) done in 2 col-halves
// so LDS = 17.4K(x) + 33.8K(h-half) -> 3 blocks/CU.
// ---------------------------------------------------------------------------
__global__ __launch_bounds__(256, 3)
void k_mlp_ln(const float* __restrict__ X, float* __restrict__ OUT,
              const short* __restrict__ w1p, const float* __restrict__ b1,
              const short* __restrict__ w2p, const float* __restrict__ b2,
              const float* __restrict__ g, const float* __restrict__ be) {
  __shared__ __align__(16) short xb[64 * 136];  // bf16 x rows, +8 pad
  __shared__ __align__(16) short hb[64 * 264];  // bf16 h half, +8 pad
  const int tid  = threadIdx.x;
  const int lane = tid & 63;
  const int wave = tid >> 6;
  const int quad = lane >> 4;
  const int ln16 = lane & 15;
  const long rowbase = (long)blockIdx.x * 64;
  const float* xsrc = X + rowbase * 128;

#pragma unroll
  for (int i = 0; i < 8; ++i) {
    int flat = tid + 256 * i;
    int r  = flat >> 5;
    int c4 = (flat & 31) << 2;
    floatx4 v = *(const floatx4*)(xsrc + r * 128 + c4);
    short4v s;
    s[0] = f2b(v[0]); s[1] = f2b(v[1]); s[2] = f2b(v[2]); s[3] = f2b(v[3]);
    *(short4v*)&xb[r * 136 + c4] = s;
  }
  __syncthreads();

  const int wr = wave * 16;
  floatx4 acc2[8];
#pragma unroll
  for (int i = 0; i < 8; ++i) acc2[i] = (floatx4){0.f, 0.f, 0.f, 0.f};

#pragma unroll 1
  for (int half = 0; half < 2; ++half) {
    // GEMM1 half: h[:, half*256 .. +256), bias+gelu -> hb (bf16)
#pragma unroll 2
    for (int nt2 = 0; nt2 < 16; ++nt2) {
      const int ntg = half * 16 + nt2;
      floatx4 acc = {0.f, 0.f, 0.f, 0.f};
#pragma unroll
      for (int ks = 0; ks < 4; ++ks) {
        short8 a = *(const short8*)&xb[(wr + ln16) * 136 + ks * 32 + quad * 8];
        short8 b = *(const short8*)&w1p[((ntg * 4 + ks) * 64 + lane) * 8];
        acc = MFMA_BF16(a, b, acc);
      }
      const float bias = b1[ntg * 16 + ln16];
#pragma unroll
      for (int r = 0; r < 4; ++r) {
        float hv = gelu_exact(acc[r] + bias);
        hb[(wr + quad * 4 + r) * 264 + nt2 * 16 + ln16] = f2b(hv);
      }
    }
    __syncthreads();
    // GEMM2 partial accumulate over this half's 256 k values
#pragma unroll 2
    for (int nt = 0; nt < 8; ++nt) {
      floatx4 a2 = acc2[nt];
#pragma unroll
      for (int ks = 0; ks < 8; ++ks) {
        short8 a = *(const short8*)&hb[(wr + ln16) * 264 + ks * 32 + quad * 8];
        short8 b = *(const short8*)&w2p[((nt * 16 + half * 8 + ks) * 64 + lane) * 8];
        a2 = MFMA_BF16(a, b, a2);
      }
      acc2[nt] = a2;
    }
    __syncthreads();
  }

  // epilogue: residual (re-read x fp32) + bias + LayerNorm, C-layout:
  // row = quad*4+reg, col = nt*16 + (lane&15)
  float gv[8], bev[8], b2v[8];
#pragma unroll
  for (int nt = 0; nt < 8; ++nt) {
    const int col = nt * 16 + ln16;
    gv[nt] = g[col]; bev[nt] = be[col]; b2v[nt] = b2[col];
  }
#pragma unroll
  for (int r = 0; r < 4; ++r) {
    const int row = wr + quad * 4 + r;
    const float* xr = xsrc + row * 128;
    float yv[8];
    float s1 = 0.f, s2 = 0.f;
#pragma unroll
    for (int nt = 0; nt < 8; ++nt) {
      float v = acc2[nt][r] + b2v[nt] + xr[nt * 16 + ln16];
      yv[nt] = v; s1 += v; s2 += v * v;
    }
#pragma unroll
    for (int off = 1; off < 16; off <<= 1) {
      s1 += __shfl_xor(s1, off, 16);
      s2 += __shfl_xor(s2, off, 16);
    }
    const float mean = s1 * (1.0f / 128.0f);
    const float rstd = rsqrtf(s2 * (1.0f / 128.0f) - mean * mean + 1e-5f);
    float* orow = OUT + (rowbase + row) * 128;
#pragma unroll
    for (int nt = 0; nt < 8; ++nt)
      orow[nt * 16 + ln16] = (yv[nt] - mean) * rstd * gv[nt] + bev[nt];
  }
}

// ---------------------------------------------------------------------------
// Stage C: buffer[bl,h,i,:] = attn1 over banded window j in [i-5, i+5] (j<=14).
// Only 15 K/V rows per (b,l) are ever needed. One block per (b,l). fp32.
// ---------------------------------------------------------------------------
__global__ __launch_bounds__(256, 2)
void k_buffer(const float* __restrict__ XP, const float* __restrict__ router,
              const float* __restrict__ w_r, const float* __restrict__ b_r,
              const float* __restrict__ w_k, const float* __restrict__ b_k,
              const float* __restrict__ w_v, const float* __restrict__ b_v,
              float* __restrict__ BUF) {
  __shared__ float xs[15 * 128];
  __shared__ float rf[10 * 128];
  __shared__ float kp[15 * 128];
  __shared__ float vp[15 * 128];
  __shared__ float rp[10 * 128];
  const int bl = blockIdx.x;
  const int b = bl >> 5, l = bl & 31;
  const int tid = threadIdx.x;

  for (int i = tid; i < 15 * 128; i += 256) {
    int t = i >> 7, c = i & 127;
    xs[i] = XP[(((long)b * 1024 + t) * 32 + l) * 128 + c];
  }
  for (int i = tid; i < 10 * 128; i += 256) rf[i] = router[(long)l * 1280 + i];
  __syncthreads();

  // 40*128 = 5120 projection outputs: 15 K rows, 15 V rows, 10 router rows
  for (int i = tid; i < 40 * 128; i += 256) {
    int t = i >> 7, c = i & 127;
    const float* xr;
    const float* W;
    float acc;
    if (t < 15)      { xr = &xs[t * 128];        W = w_k; acc = b_k[c]; }
    else if (t < 30) { xr = &xs[(t - 15) * 128]; W = w_v; acc = b_v[c]; }
    else             { xr = &rf[(t - 30) * 128]; W = w_r; acc = b_r[c]; }
    for (int d = 0; d < 128; ++d) acc += xr[d] * W[d * 128 + c];
    if (t < 15)      kp[t * 128 + c] = acc;
    else if (t < 30) vp[(t - 15) * 128 + c] = acc;
    else             rp[(t - 30) * 128 + c] = acc;
  }
  __syncthreads();

  if (tid < 20) {
    const int i = tid >> 1, hd = tid & 1;
    const int jlo = (i - 5 < 0) ? 0 : i - 5;
    const int jhi = i + 5;  // <= 14
    float sc[15];
    float mx = -1e30f;
    for (int j = jlo; j <= jhi; ++j) {
      float s = 0.f;
      for (int d = 0; d < 64; ++d) s += rp[i * 128 + hd * 64 + d] * kp[j * 128 + hd * 64 + d];
      s *= 0.125f;
      s = fminf(fmaxf(s, -10000.0f), 10000.0f);
      sc[j] = s; mx = fmaxf(mx, s);
    }
    float den = 0.f;
    for (int j = jlo; j <= jhi; ++j) { sc[j] = expf(sc[j] - mx); den += sc[j]; }
    const float rden = 1.0f / den;
    for (int d = 0; d < 64; ++d) {
      float o = 0.f;
      for (int j = jlo; j <= jhi; ++j) o += sc[j] * vp[j * 128 + hd * 64 + d];
      BUF[((bl * 2 + hd) * 10 + i) * 64 + d] = o * rden;
    }
  }
}

// ---------------------------------------------------------------------------
// Stage D: per (b,l,t-tile of 64): q = x_proj@Wq+bq; attn2 over 10 buffer
// slots (banded only for t<10); recv -> MLP2 -> +x_proj -> LN2 -> LN3 -> out.
// qf (fp32) and hb (bf16 h-half) share one LDS union (both 33792 B).
// ---------------------------------------------------------------------------
__global__ __launch_bounds__(256, 2)
void k_attn_mlp(const float* __restrict__ XP, const float* __restrict__ BUF,
                float* __restrict__ OUT,
                const short* __restrict__ wqp, const float* __restrict__ bq,
                const short* __restrict__ w1p, const float* __restrict__ b1,
                const short* __restrict__ w2p, const float* __restrict__ b2,
                const float* __restrict__ g2, const float* __restrict__ be2,
                const float* __restrict__ g3, const float* __restrict__ be3) {
  __shared__ __align__(16) short xb[64 * 136];   // x_proj bf16, later recv bf16
  __shared__ __align__(16) char uni[64 * 264 * 2];  // qf fp32[64][132] | hb bf16[64][264]
  __shared__ __align__(16) float kv[2 * 10 * 64];
  float* qf = (float*)uni;
  short* hb = (short*)uni;

  const int tid  = threadIdx.x;
  const int lane = tid & 63;
  const int wave = tid >> 6;
  const int quad = lane >> 4;
  const int ln16 = lane & 15;

  const int bx = blockIdx.x;
  const int bl = bx >> 4;
  const int tt = bx & 15;
  const int b = bl >> 5, l = bl & 31;
  const int t0 = tt * 64;
  const long basef = ((long)(b * 1024 + t0) * 32 + l) * 128;  // row stride 4096

#pragma unroll
  for (int i = 0; i < 8; ++i) {
    int flat = tid + 256 * i;
    int r  = flat >> 5;
    int c4 = (flat & 31) << 2;
    floatx4 v = *(const floatx4*)(XP + basef + (long)r * 4096 + c4);
    short4v s;
    s[0] = f2b(v[0]); s[1] = f2b(v[1]); s[2] = f2b(v[2]); s[3] = f2b(v[3]);
    *(short4v*)&xb[r * 136 + c4] = s;
  }
  for (int i = tid; i < 1280; i += 256) kv[i] = BUF[bl * 1280 + i];
  __syncthreads();

  const int wr = wave * 16;
  // q projection -> qf (fp32)
#pragma unroll 2
  for (int nt = 0; nt < 8; ++nt) {
    floatx4 acc = {0.f, 0.f, 0.f, 0.f};
#pragma unroll
    for (int ks = 0; ks < 4; ++ks) {
      short8 a  = *(const short8*)&xb[(wr + ln16) * 136 + ks * 32 + quad * 8];
      short8 bb = *(const short8*)&wqp[((nt * 4 + ks) * 64 + lane) * 8];
      acc = MFMA_BF16(a, bb, acc);
    }
    const float bias = bq[nt * 16 + ln16];
#pragma unroll
    for (int r = 0; r < 4; ++r)
      qf[(wr + quad * 4 + r) * 132 + nt * 16 + ln16] = acc[r] + bias;
  }
  __syncthreads();

  // attention over 10 buffer slots; recv written as bf16 into xb
  if (tid < 128) {
    const int row = tid >> 1, hd = tid & 1;
    const int t = t0 + row;
    int jlo = 0, jhi = 9;
    if (t < 10) { jlo = (t - 5 < 0) ? 0 : t - 5; jhi = (t + 5 > 9) ? 9 : t + 5; }
    const float* qrow = &qf[row * 132 + hd * 64];
    float p[10];
    float mx = -1e30f;
    for (int j = jlo; j <= jhi; ++j) {
      const float* krow = &kv[(hd * 10 + j) * 64];
      float s = 0.f;
#pragma unroll
      for (int d = 0; d < 64; d += 4) {
        floatx4 qa = *(const floatx4*)(qrow + d);
        floatx4 ka = *(const floatx4*)(krow + d);
        s += qa[0] * ka[0] + qa[1] * ka[1] + qa[2] * ka[2] + qa[3] * ka[3];
      }
      s *= 0.125f;
      s = fminf(fmaxf(s, -10000.0f), 10000.0f);
      p[j] = s; mx = fmaxf(mx, s);
    }
    float den = 0.f;
    for (int j = jlo; j <= jhi; ++j) { p[j] = expf(p[j] - mx); den += p[j]; }
    const float rden = 1.0f / den;
    for (int d = 0; d < 64; d += 4) {
      float o0 = 0.f, o1 = 0.f, o2 = 0.f, o3 = 0.f;
      for (int j = jlo; j <= jhi; ++j) {
        const float* vr = &kv[(hd * 10 + j) * 64 + d];
        const float pj = p[j] * rden;
        o0 += pj * vr[0]; o1 += pj * vr[1]; o2 += pj * vr[2]; o3 += pj * vr[3];
      }
      short4v s;
      s[0] = f2b(o0); s[1] = f2b(o1); s[2] = f2b(o2); s[3] = f2b(o3);
      *(short4v*)&xb[row * 136 + hd * 64 + d] = s;
    }
  }
  __syncthreads();

  // MLP2 on recv (xb), same two-half structure as stage B; hb overlays qf.
  floatx4 acc2[8];
#pragma unroll
  for (int i = 0; i < 8; ++i) acc2[i] = (floatx4){0.f, 0.f, 0.f, 0.f};

#pragma unroll 1
  for (int half = 0; half < 2; ++half) {
#pragma unroll 2
    for (int nt2 = 0; nt2 < 16; ++nt2) {
      const int ntg = half * 16 + nt2;
      floatx4 acc = {0.f, 0.f, 0.f, 0.f};
#pragma unroll
      for (int ks = 0; ks < 4; ++ks) {
        short8 a  = *(const short8*)&xb[(wr + ln16) * 136 + ks * 32 + quad * 8];
        short8 bb = *(const short8*)&w1p[((ntg * 4 + ks) * 64 + lane) * 8];
        acc = MFMA_BF16(a, bb, acc);
      }
      const float bias = b1[ntg * 16 + ln16];
#pragma unroll
      for (int r = 0; r < 4; ++r) {
        float hv = gelu_exact(acc[r] + bias);
        hb[(wr + quad * 4 + r) * 264 + nt2 * 16 + ln16] = f2b(hv);
      }
    }
    __syncthreads();
#pragma unroll 2
    for (int nt = 0; nt < 8; ++nt) {
      floatx4 a2 = acc2[nt];
#pragma unroll
      for (int ks = 0; ks < 8; ++ks) {
        short8 a  = *(const short8*)&hb[(wr + ln16) * 264 + ks * 32 + quad * 8];
        short8 bb = *(const short8*)&w2p[((nt * 16 + half * 8 + ks) * 64 + lane) * 8];
        a2 = MFMA_BF16(a, bb, a2);
      }
      acc2[nt] = a2;
    }
    __syncthreads();
  }

  // epilogue: + x_proj residual (fp32 re-read), LN2 then LN3, write out
  float g2v[8], be2v[8], g3v[8], be3v[8], b2v[8];
#pragma unroll
  for (int nt = 0; nt < 8; ++nt) {
    const int col = nt * 16 + ln16;
    g2v[nt] = g2[col]; be2v[nt] = be2[col];
    g3v[nt] = g3[col]; be3v[nt] = be3[col];
    b2v[nt] = b2[col];
  }
#pragma unroll
  for (int r = 0; r < 4; ++r) {
    const int row = wr + quad * 4 + r;
    const float* xr = XP + basef + (long)row * 4096;
    float yv[8];
    float s1 = 0.f, s2 = 0.f;
#pragma unroll
    for (int nt = 0; nt < 8; ++nt) {
      float v = acc2[nt][r] + b2v[nt] + xr[nt * 16 + ln16];
      yv[nt] = v; s1 += v; s2 += v * v;
    }
#pragma unroll
    for (int off = 1; off < 16; off <<= 1) {
      s1 += __shfl_xor(s1, off, 16);
      s2 += __shfl_xor(s2, off, 16);
    }
    float mean = s1 * (1.0f / 128.0f);
    float rstd = rsqrtf(s2 * (1.0f / 128.0f) - mean * mean + 1e-5f);
    float zv[8];
    s1 = 0.f; s2 = 0.f;
#pragma unroll
    for (int nt = 0; nt < 8; ++nt) {
      float z = (yv[nt] - mean) * rstd * g2v[nt] + be2v[nt];
      zv[nt] = z; s1 += z; s2 += z * z;
    }
#pragma unroll
    for (int off = 1; off < 16; off <<= 1) {
      s1 += __shfl_xor(s1, off, 16);
      s2 += __shfl_xor(s2, off, 16);
    }
    mean = s1 * (1.0f / 128.0f);
    rstd = rsqrtf(s2 * (1.0f / 128.0f) - mean * mean + 1e-5f);
    float* orow = OUT + basef + (long)row * 4096;
#pragma unroll
    for (int nt = 0; nt < 8; ++nt)
      orow[nt * 16 + ln16] = (zv[nt] - mean) * rstd * g3v[nt] + be3v[nt];
  }
}

// ---------------------------------------------------------------------------
extern "C" void kernel_launch(void* const* d_in, const int* in_sizes, int n_in,
                              void* d_out, int out_size, void* d_ws, size_t ws_size,
                              hipStream_t stream) {
  const float* x        = (const float*)d_in[0];
  const float* router   = (const float*)d_in[1];
  const float* w_router = (const float*)d_in[2];
  const float* b_router = (const float*)d_in[3];
  const float* w_k  = (const float*)d_in[4];
  const float* b_k  = (const float*)d_in[5];
  const float* w_v  = (const float*)d_in[6];
  const float* b_v  = (const float*)d_in[7];
  const float* w_q  = (const float*)d_in[8];
  const float* b_q  = (const float*)d_in[9];
  const float* m1w1 = (const float*)d_in[10];
  const float* m1b1 = (const float*)d_in[11];
  const float* m1w2 = (const float*)d_in[12];
  const float* m1b2 = (const float*)d_in[13];
  const float* m2w1 = (const float*)d_in[14];
  const float* m2b1 = (const float*)d_in[15];
  const float* m2w2 = (const float*)d_in[16];
  const float* m2b2 = (const float*)d_in[17];
  const float* g1  = (const float*)d_in[18];
  const float* be1 = (const float*)d_in[19];
  const float* g2  = (const float*)d_in[20];
  const float* be2 = (const float*)d_in[21];
  const float* g3  = (const float*)d_in[22];
  const float* be3 = (const float*)d_in[23];
  float* out = (float*)d_out;

  // workspace layout
  char* ws = (char*)d_ws;
  float* XP  = (float*)ws;                     // x_proj fp32: 131072*128*4 = 64 MiB
  float* BUF = (float*)(ws + 67108864);        // buffer fp32: 128*2*10*64*4 = 640 KiB
  short* w1p1 = (short*)(ws + 67764224);       // packed bf16 weights
  short* w2p1 = w1p1 + 65536;
  short* w1p2 = w2p1 + 65536;
  short* w2p2 = w1p2 + 65536;
  short* wqp  = w2p2 + 65536;                  // 16384 shorts

  pack_w<<<256, 256, 0, stream>>>(m1w1, w1p1, 4, 512, 65536);   // W1: K=128,N=512
  pack_w<<<256, 256, 0, stream>>>(m1w2, w2p1, 16, 128, 65536);  // W2: K=512,N=128
  pack_w<<<256, 256, 0, stream>>>(m2w1, w1p2, 4, 512, 65536);
  pack_w<<<256, 256, 0, stream>>>(m2w2, w2p2, 16, 128, 65536);
  pack_w<<<64, 256, 0, stream>>>(w_q, wqp, 4, 128, 16384);      // Wq: K=128,N=128

  k_mlp_ln<<<2048, 256, 0, stream>>>(x, XP, w1p1, m1b1, w2p1, m1b2, g1, be1);
  k_buffer<<<128, 256, 0, stream>>>(XP, router, w_router, b_router,
                                    w_k, b_k, w_v, b_v, BUF);
  k_attn_mlp<<<2048, 256, 0, stream>>>(XP, BUF, out, wqp, b_q,
                                       w1p2, m2b1, w2p2, m2b2,
                                       g2, be2, g3, be3);
}

// Round 2
// 761.583 us; speedup vs baseline: 1.0095x; 1.0095x over previous
//
#include <hip/hip_runtime.h>
#include <math.h>

// ---------------------------------------------------------------------------
// QuadraLayer fused, bf16-MFMA path, round 2.
// Changes vs r1: quarter-sized h tiles + bf16 q => LDS <= 40KB => 4 blocks/CU
// in both big kernels; x_proj stored bf16 (halves XP traffic); packs merged.
// ---------------------------------------------------------------------------

typedef short short8 __attribute__((ext_vector_type(8)));
typedef short short4v __attribute__((ext_vector_type(4)));
typedef float floatx4 __attribute__((ext_vector_type(4)));

#define MFMA_BF16(a, b, c) __builtin_amdgcn_mfma_f32_16x16x32_bf16((a), (b), (c), 0, 0, 0)

__device__ __forceinline__ short f2b(float f) {
  unsigned u = __builtin_bit_cast(unsigned, f);
  u += 0x7FFFu + ((u >> 16) & 1u);
  return (short)(u >> 16);
}
__device__ __forceinline__ float b2f(short s) {
  unsigned u = ((unsigned)(unsigned short)s) << 16;
  return __builtin_bit_cast(float, u);
}
__device__ __forceinline__ float gelu_exact(float v) {
  return 0.5f * v * (1.0f + erff(v * 0.70710678118654752f));
}

// ---------------------------------------------------------------------------
// Pack all weights into MFMA B-fragment order (bf16), one launch.
// B-frag: lane holds B[k = ks*32 + (lane>>4)*8 + j][n = nt*16 + (lane&15)]
// ---------------------------------------------------------------------------
__global__ void pack_all(const float* __restrict__ m1w1, const float* __restrict__ m1w2,
                         const float* __restrict__ m2w1, const float* __restrict__ m2w2,
                         const float* __restrict__ wq,
                         short* __restrict__ w1p1, short* __restrict__ w2p1,
                         short* __restrict__ w1p2, short* __restrict__ w2p2,
                         short* __restrict__ wqp) {
  int idx = blockIdx.x * 256 + threadIdx.x;
  const float* W; short* P; int KS, N, base;
  if (idx < 65536)       { W = m1w1; P = w1p1; KS = 4;  N = 512; base = 0; }
  else if (idx < 131072) { W = m1w2; P = w2p1; KS = 16; N = 128; base = 65536; }
  else if (idx < 196608) { W = m2w1; P = w1p2; KS = 4;  N = 512; base = 131072; }
  else if (idx < 262144) { W = m2w2; P = w2p2; KS = 16; N = 128; base = 196608; }
  else if (idx < 278528) { W = wq;   P = wqp;  KS = 4;  N = 128; base = 262144; }
  else return;
  int i = idx - base;
  int j    = i & 7;
  int lane = (i >> 3) & 63;
  int ks   = (i >> 9) % KS;
  int nt   = i / (KS << 9);
  int k = ks * 32 + ((lane >> 4) << 3) + j;
  int n = nt * 16 + (lane & 15);
  P[i] = f2b(W[k * N + n]);
}

// ---------------------------------------------------------------------------
// Stage B: x_proj(bf16) = LN(x + MLP1(x)). 64 rows/block, h in 4 quarters.
// LDS = 17408 + 17408 = 34816 B -> 4 blocks/CU.
// ---------------------------------------------------------------------------
__global__ __launch_bounds__(256, 4)
void k_mlp_ln(const float* __restrict__ X, short* __restrict__ OUTb,
              const short* __restrict__ w1p, const float* __restrict__ b1,
              const short* __restrict__ w2p, const float* __restrict__ b2,
              const float* __restrict__ g, const float* __restrict__ be) {
  __shared__ __align__(16) short xb[64 * 136];
  __shared__ __align__(16) short hb[64 * 136];
  const int tid  = threadIdx.x;
  const int lane = tid & 63;
  const int wave = tid >> 6;
  const int quad = lane >> 4;
  const int ln16 = lane & 15;
  const long rowbase = (long)blockIdx.x * 64;
  const float* xsrc = X + rowbase * 128;

#pragma unroll
  for (int i = 0; i < 8; ++i) {
    int flat = tid + 256 * i;
    int r  = flat >> 5;
    int c4 = (flat & 31) << 2;
    floatx4 v = *(const floatx4*)(xsrc + r * 128 + c4);
    short4v s;
    s[0] = f2b(v[0]); s[1] = f2b(v[1]); s[2] = f2b(v[2]); s[3] = f2b(v[3]);
    *(short4v*)&xb[r * 136 + c4] = s;
  }
  __syncthreads();

  const int wr = wave * 16;
  floatx4 acc2[8];
#pragma unroll
  for (int i = 0; i < 8; ++i) acc2[i] = (floatx4){0.f, 0.f, 0.f, 0.f};

#pragma unroll 1
  for (int qtr = 0; qtr < 4; ++qtr) {
#pragma unroll 2
    for (int nt2 = 0; nt2 < 8; ++nt2) {
      const int ntg = qtr * 8 + nt2;
      floatx4 acc = {0.f, 0.f, 0.f, 0.f};
#pragma unroll
      for (int ks = 0; ks < 4; ++ks) {
        short8 a = *(const short8*)&xb[(wr + ln16) * 136 + ks * 32 + quad * 8];
        short8 b = *(const short8*)&w1p[((ntg * 4 + ks) * 64 + lane) * 8];
        acc = MFMA_BF16(a, b, acc);
      }
      const float bias = b1[ntg * 16 + ln16];
#pragma unroll
      for (int r = 0; r < 4; ++r) {
        float hv = gelu_exact(acc[r] + bias);
        hb[(wr + quad * 4 + r) * 136 + nt2 * 16 + ln16] = f2b(hv);
      }
    }
    __syncthreads();
#pragma unroll 2
    for (int nt = 0; nt < 8; ++nt) {
      floatx4 a2 = acc2[nt];
#pragma unroll
      for (int ks = 0; ks < 4; ++ks) {
        short8 a = *(const short8*)&hb[(wr + ln16) * 136 + ks * 32 + quad * 8];
        short8 b = *(const short8*)&w2p[((nt * 16 + qtr * 4 + ks) * 64 + lane) * 8];
        a2 = MFMA_BF16(a, b, a2);
      }
      acc2[nt] = a2;
    }
    __syncthreads();
  }

  // epilogue: residual (x fp32) + bias + LN, write bf16 x_proj
  float gv[8], bev[8], b2v[8];
#pragma unroll
  for (int nt = 0; nt < 8; ++nt) {
    const int col = nt * 16 + ln16;
    gv[nt] = g[col]; bev[nt] = be[col]; b2v[nt] = b2[col];
  }
#pragma unroll
  for (int r = 0; r < 4; ++r) {
    const int row = wr + quad * 4 + r;
    const float* xr = xsrc + row * 128;
    float yv[8];
    float s1 = 0.f, s2 = 0.f;
#pragma unroll
    for (int nt = 0; nt < 8; ++nt) {
      float v = acc2[nt][r] + b2v[nt] + xr[nt * 16 + ln16];
      yv[nt] = v; s1 += v; s2 += v * v;
    }
#pragma unroll
    for (int off = 1; off < 16; off <<= 1) {
      s1 += __shfl_xor(s1, off, 16);
      s2 += __shfl_xor(s2, off, 16);
    }
    const float mean = s1 * (1.0f / 128.0f);
    const float rstd = rsqrtf(s2 * (1.0f / 128.0f) - mean * mean + 1e-5f);
    short* orow = OUTb + (rowbase + row) * 128;
#pragma unroll
    for (int nt = 0; nt < 8; ++nt)
      orow[nt * 16 + ln16] = f2b((yv[nt] - mean) * rstd * gv[nt] + bev[nt]);
  }
}

// ---------------------------------------------------------------------------
// Stage C: banded attn1 -> buffer. Only t<15 K/V rows matter. 1 block/(b,l).
// ---------------------------------------------------------------------------
__global__ __launch_bounds__(256, 2)
void k_buffer(const short* __restrict__ XPb, const float* __restrict__ router,
              const float* __restrict__ w_r, const float* __restrict__ b_r,
              const float* __restrict__ w_k, const float* __restrict__ b_k,
              const float* __restrict__ w_v, const float* __restrict__ b_v,
              float* __restrict__ BUF) {
  __shared__ float xs[15 * 128];
  __shared__ float rf[10 * 128];
  __shared__ float kp[15 * 128];
  __shared__ float vp[15 * 128];
  __shared__ float rp[10 * 128];
  const int bl = blockIdx.x;
  const int b = bl >> 5, l = bl & 31;
  const int tid = threadIdx.x;

  for (int i = tid; i < 15 * 128; i += 256) {
    int t = i >> 7, c = i & 127;
    xs[i] = b2f(XPb[(((long)b * 1024 + t) * 32 + l) * 128 + c]);
  }
  for (int i = tid; i < 10 * 128; i += 256) rf[i] = router[(long)l * 1280 + i];
  __syncthreads();

  for (int i = tid; i < 40 * 128; i += 256) {
    int t = i >> 7, c = i & 127;
    const float* xr;
    const float* W;
    float acc;
    if (t < 15)      { xr = &xs[t * 128];        W = w_k; acc = b_k[c]; }
    else if (t < 30) { xr = &xs[(t - 15) * 128]; W = w_v; acc = b_v[c]; }
    else             { xr = &rf[(t - 30) * 128]; W = w_r; acc = b_r[c]; }
    float a0 = 0.f, a1 = 0.f, a2 = 0.f, a3 = 0.f;
    for (int d = 0; d < 128; d += 4) {
      a0 += xr[d]     * W[d * 128 + c];
      a1 += xr[d + 1] * W[(d + 1) * 128 + c];
      a2 += xr[d + 2] * W[(d + 2) * 128 + c];
      a3 += xr[d + 3] * W[(d + 3) * 128 + c];
    }
    acc += (a0 + a1) + (a2 + a3);
    if (t < 15)      kp[t * 128 + c] = acc;
    else if (t < 30) vp[(t - 15) * 128 + c] = acc;
    else             rp[(t - 30) * 128 + c] = acc;
  }
  __syncthreads();

  if (tid < 20) {
    const int i = tid >> 1, hd = tid & 1;
    const int jlo = (i - 5 < 0) ? 0 : i - 5;
    const int jhi = i + 5;  // <= 14
    float sc[15];
    float mx = -1e30f;
    for (int j = jlo; j <= jhi; ++j) {
      float s = 0.f;
      for (int d = 0; d < 64; ++d) s += rp[i * 128 + hd * 64 + d] * kp[j * 128 + hd * 64 + d];
      s *= 0.125f;
      s = fminf(fmaxf(s, -10000.0f), 10000.0f);
      sc[j] = s; mx = fmaxf(mx, s);
    }
    float den = 0.f;
    for (int j = jlo; j <= jhi; ++j) { sc[j] = expf(sc[j] - mx); den += sc[j]; }
    const float rden = 1.0f / den;
    for (int d = 0; d < 64; ++d) {
      float o = 0.f;
      for (int j = jlo; j <= jhi; ++j) o += sc[j] * vp[j * 128 + hd * 64 + d];
      BUF[((bl * 2 + hd) * 10 + i) * 64 + d] = o * rden;
    }
  }
}

// ---------------------------------------------------------------------------
// Stage D: q-proj + attn2(10 keys) + MLP2 + LN2 + LN3 -> out.
// LDS = xb 17408 + union(q bf16 / h quarter) 17408 + kv 5120 = 39936 B
// -> 4 blocks/CU.
// ---------------------------------------------------------------------------
__global__ __launch_bounds__(256, 4)
void k_attn_mlp(const short* __restrict__ XPb, const float* __restrict__ BUF,
                float* __restrict__ OUT,
                const short* __restrict__ wqp, const float* __restrict__ bq,
                const short* __restrict__ w1p, const float* __restrict__ b1,
                const short* __restrict__ w2p, const float* __restrict__ b2,
                const float* __restrict__ g2, const float* __restrict__ be2,
                const float* __restrict__ g3, const float* __restrict__ be3) {
  __shared__ __align__(16) short xb[64 * 136];  // x_proj bf16, later recv bf16
  __shared__ __align__(16) short qh[64 * 136];  // q bf16, later h-quarter bf16
  __shared__ __align__(16) float kv[2 * 10 * 64];

  const int tid  = threadIdx.x;
  const int lane = tid & 63;
  const int wave = tid >> 6;
  const int quad = lane >> 4;
  const int ln16 = lane & 15;

  const int bx = blockIdx.x;
  const int bl = bx >> 4;
  const int tt = bx & 15;
  const int b = bl >> 5, l = bl & 31;
  const int t0 = tt * 64;
  const long basef = ((long)(b * 1024 + t0) * 32 + l) * 128;  // row stride 4096

  // stage x_proj bf16 rows straight into LDS (short8 = 16 B loads)
#pragma unroll
  for (int i = 0; i < 4; ++i) {
    int flat = tid + 256 * i;
    int r  = flat >> 4;
    int c8 = (flat & 15) << 3;
    short8 v = *(const short8*)(XPb + basef + (long)r * 4096 + c8);
    *(short8*)&xb[r * 136 + c8] = v;
  }
  for (int i = tid; i < 1280; i += 256) kv[i] = BUF[bl * 1280 + i];
  __syncthreads();

  const int wr = wave * 16;
  // q projection -> qh (bf16)
#pragma unroll 2
  for (int nt = 0; nt < 8; ++nt) {
    floatx4 acc = {0.f, 0.f, 0.f, 0.f};
#pragma unroll
    for (int ks = 0; ks < 4; ++ks) {
      short8 a  = *(const short8*)&xb[(wr + ln16) * 136 + ks * 32 + quad * 8];
      short8 bb = *(const short8*)&wqp[((nt * 4 + ks) * 64 + lane) * 8];
      acc = MFMA_BF16(a, bb, acc);
    }
    const float bias = bq[nt * 16 + ln16];
#pragma unroll
    for (int r = 0; r < 4; ++r)
      qh[(wr + quad * 4 + r) * 136 + nt * 16 + ln16] = f2b(acc[r] + bias);
  }
  __syncthreads();

  // attention over 10 buffer slots; recv written bf16 into xb
  if (tid < 128) {
    const int row = tid >> 1, hd = tid & 1;
    const int t = t0 + row;
    int jlo = 0, jhi = 9;
    if (t < 10) { jlo = (t - 5 < 0) ? 0 : t - 5; jhi = (t + 5 > 9) ? 9 : t + 5; }
    const short* qrow = &qh[row * 136 + hd * 64];
    float p[10];
#pragma unroll
    for (int j = 0; j < 10; ++j) p[j] = 0.f;
    // d-outer, j-inner keeps register count low
    for (int d = 0; d < 64; ++d) {
      const float qd = b2f(qrow[d]);
      for (int j = jlo; j <= jhi; ++j) p[j] += qd * kv[(hd * 10 + j) * 64 + d];
    }
    float mx = -1e30f;
    for (int j = jlo; j <= jhi; ++j) {
      float s = p[j] * 0.125f;
      s = fminf(fmaxf(s, -10000.0f), 10000.0f);
      p[j] = s; mx = fmaxf(mx, s);
    }
    float den = 0.f;
    for (int j = jlo; j <= jhi; ++j) { p[j] = expf(p[j] - mx); den += p[j]; }
    const float rden = 1.0f / den;
    for (int d = 0; d < 64; d += 4) {
      float o0 = 0.f, o1 = 0.f, o2 = 0.f, o3 = 0.f;
      for (int j = jlo; j <= jhi; ++j) {
        const float* vr = &kv[(hd * 10 + j) * 64 + d];
        const float pj = p[j] * rden;
        o0 += pj * vr[0]; o1 += pj * vr[1]; o2 += pj * vr[2]; o3 += pj * vr[3];
      }
      short4v s;
      s[0] = f2b(o0); s[1] = f2b(o1); s[2] = f2b(o2); s[3] = f2b(o3);
      *(short4v*)&xb[row * 136 + hd * 64 + d] = s;
    }
  }
  __syncthreads();

  // MLP2 on recv (xb), h in quarters through qh
  floatx4 acc2[8];
#pragma unroll
  for (int i = 0; i < 8; ++i) acc2[i] = (floatx4){0.f, 0.f, 0.f, 0.f};

#pragma unroll 1
  for (int qtr = 0; qtr < 4; ++qtr) {
#pragma unroll 2
    for (int nt2 = 0; nt2 < 8; ++nt2) {
      const int ntg = qtr * 8 + nt2;
      floatx4 acc = {0.f, 0.f, 0.f, 0.f};
#pragma unroll
      for (int ks = 0; ks < 4; ++ks) {
        short8 a  = *(const short8*)&xb[(wr + ln16) * 136 + ks * 32 + quad * 8];
        short8 bb = *(const short8*)&w1p[((ntg * 4 + ks) * 64 + lane) * 8];
        acc = MFMA_BF16(a, bb, acc);
      }
      const float bias = b1[ntg * 16 + ln16];
#pragma unroll
      for (int r = 0; r < 4; ++r) {
        float hv = gelu_exact(acc[r] + bias);
        qh[(wr + quad * 4 + r) * 136 + nt2 * 16 + ln16] = f2b(hv);
      }
    }
    __syncthreads();
#pragma unroll 2
    for (int nt = 0; nt < 8; ++nt) {
      floatx4 a2 = acc2[nt];
#pragma unroll
      for (int ks = 0; ks < 4; ++ks) {
        short8 a  = *(const short8*)&qh[(wr + ln16) * 136 + ks * 32 + quad * 8];
        short8 bb = *(const short8*)&w2p[((nt * 16 + qtr * 4 + ks) * 64 + lane) * 8];
        a2 = MFMA_BF16(a, bb, a2);
      }
      acc2[nt] = a2;
    }
    __syncthreads();
  }

  // epilogue: + x_proj residual (bf16 re-read), LN2 then LN3, write out
  float g2v[8], be2v[8], g3v[8], be3v[8], b2v[8];
#pragma unroll
  for (int nt = 0; nt < 8; ++nt) {
    const int col = nt * 16 + ln16;
    g2v[nt] = g2[col]; be2v[nt] = be2[col];
    g3v[nt] = g3[col]; be3v[nt] = be3[col];
    b2v[nt] = b2[col];
  }
#pragma unroll
  for (int r = 0; r < 4; ++r) {
    const int row = wr + quad * 4 + r;
    const short* xrb = XPb + basef + (long)row * 4096;
    float yv[8];
    float s1 = 0.f, s2 = 0.f;
#pragma unroll
    for (int nt = 0; nt < 8; ++nt) {
      float v = acc2[nt][r] + b2v[nt] + b2f(xrb[nt * 16 + ln16]);
      yv[nt] = v; s1 += v; s2 += v * v;
    }
#pragma unroll
    for (int off = 1; off < 16; off <<= 1) {
      s1 += __shfl_xor(s1, off, 16);
      s2 += __shfl_xor(s2, off, 16);
    }
    float mean = s1 * (1.0f / 128.0f);
    float rstd = rsqrtf(s2 * (1.0f / 128.0f) - mean * mean + 1e-5f);
    float zv[8];
    s1 = 0.f; s2 = 0.f;
#pragma unroll
    for (int nt = 0; nt < 8; ++nt) {
      float z = (yv[nt] - mean) * rstd * g2v[nt] + be2v[nt];
      zv[nt] = z; s1 += z; s2 += z * z;
    }
#pragma unroll
    for (int off = 1; off < 16; off <<= 1) {
      s1 += __shfl_xor(s1, off, 16);
      s2 += __shfl_xor(s2, off, 16);
    }
    mean = s1 * (1.0f / 128.0f);
    rstd = rsqrtf(s2 * (1.0f / 128.0f) - mean * mean + 1e-5f);
    float* orow = OUT + basef + (long)row * 4096;
#pragma unroll
    for (int nt = 0; nt < 8; ++nt)
      orow[nt * 16 + ln16] = (zv[nt] - mean) * rstd * g3v[nt] + be3v[nt];
  }
}

// ---------------------------------------------------------------------------
extern "C" void kernel_launch(void* const* d_in, const int* in_sizes, int n_in,
                              void* d_out, int out_size, void* d_ws, size_t ws_size,
                              hipStream_t stream) {
  const float* x        = (const float*)d_in[0];
  const float* router   = (const float*)d_in[1];
  const float* w_router = (const float*)d_in[2];
  const float* b_router = (const float*)d_in[3];
  const float* w_k  = (const float*)d_in[4];
  const float* b_k  = (const float*)d_in[5];
  const float* w_v  = (const float*)d_in[6];
  const float* b_v  = (const float*)d_in[7];
  const float* w_q  = (const float*)d_in[8];
  const float* b_q  = (const float*)d_in[9];
  const float* m1w1 = (const float*)d_in[10];
  const float* m1b1 = (const float*)d_in[11];
  const float* m1w2 = (const float*)d_in[12];
  const float* m1b2 = (const float*)d_in[13];
  const float* m2w1 = (const float*)d_in[14];
  const float* m2b1 = (const float*)d_in[15];
  const float* m2w2 = (const float*)d_in[16];
  const float* m2b2 = (const float*)d_in[17];
  const float* g1  = (const float*)d_in[18];
  const float* be1 = (const float*)d_in[19];
  const float* g2  = (const float*)d_in[20];
  const float* be2 = (const float*)d_in[21];
  const float* g3  = (const float*)d_in[22];
  const float* be3 = (const float*)d_in[23];
  float* out = (float*)d_out;

  // workspace layout
  char* ws = (char*)d_ws;
  short* XPb = (short*)ws;                      // x_proj bf16: 131072*128*2 = 32 MiB
  float* BUF = (float*)(ws + 33554432);         // 128*2*10*64*4 = 640 KiB
  short* w1p1 = (short*)(ws + 34209792);
  short* w2p1 = w1p1 + 65536;
  short* w1p2 = w2p1 + 65536;
  short* w2p2 = w1p2 + 65536;
  short* wqp  = w2p2 + 65536;                   // 16384 shorts

  pack_all<<<1088, 256, 0, stream>>>(m1w1, m1w2, m2w1, m2w2, w_q,
                                     w1p1, w2p1, w1p2, w2p2, wqp);
  k_mlp_ln<<<2048, 256, 0, stream>>>(x, XPb, w1p1, m1b1, w2p1, m1b2, g1, be1);
  k_buffer<<<128, 256, 0, stream>>>(XPb, router, w_router, b_router,
                                    w_k, b_k, w_v, b_v, BUF);
  k_attn_mlp<<<2048, 256, 0, stream>>>(XPb, BUF, out, wqp, b_q,
                                       w1p2, m2b1, w2p2, m2b2,
                                       g2, be2, g3, be3);
}

// Round 3
// 670.710 us; speedup vs baseline: 1.1463x; 1.1355x over previous
//
#include <hip/hip_runtime.h>
#include <math.h>

// ---------------------------------------------------------------------------
// QuadraLayer fused, bf16-MFMA path, round 3.
// Key change: GEMMs computed transposed (weights = A operand, activations = B
// operand) so each lane's C fragment holds 4 CONSECUTIVE output dims of one
// activation row -> vectorized h writes (ds_write_b64), vectorized bias/
// residual/gamma/beta loads, 2-shuffle LN reductions. Fast branch-free erf
// replaces libm erff. Attention j-loops fully static (band handled by mask).
// ---------------------------------------------------------------------------

typedef short short8 __attribute__((ext_vector_type(8)));
typedef short short4v __attribute__((ext_vector_type(4)));
typedef float floatx4 __attribute__((ext_vector_type(4)));

#define MFMA_BF16(a, b, c) __builtin_amdgcn_mfma_f32_16x16x32_bf16((a), (b), (c), 0, 0, 0)

__device__ __forceinline__ short f2b(float f) {
  unsigned u = __builtin_bit_cast(unsigned, f);
  u += 0x7FFFu + ((u >> 16) & 1u);
  return (short)(u >> 16);
}
__device__ __forceinline__ float b2f(short s) {
  unsigned u = ((unsigned)(unsigned short)s) << 16;
  return __builtin_bit_cast(float, u);
}
// gelu(v) = 0.5 v (1+erf(v/sqrt2)); erf via A&S 7.1.26 (|eps|<=1.5e-7), branch-free
__device__ __forceinline__ float gelu_fast(float v) {
  float z  = v * 0.70710678118654752f;
  float az = fabsf(z);
  float t  = __builtin_amdgcn_rcpf(1.0f + 0.3275911f * az);
  float poly = ((((1.061405429f * t - 1.453152027f) * t + 1.421413741f) * t
                 - 0.284496736f) * t + 0.254829592f) * t;
  float e = 1.0f - poly * __expf(-az * az);
  float erfv = copysignf(e, z);
  return 0.5f * v * (1.0f + erfv);
}

// ---------------------------------------------------------------------------
// Pack all weights into bf16 MFMA fragments (same bytes serve as A- or B-
// operand: lane -> (free dim = lane&15, k = (lane>>4)*8+j)).
// ---------------------------------------------------------------------------
__global__ void pack_all(const float* __restrict__ m1w1, const float* __restrict__ m1w2,
                         const float* __restrict__ m2w1, const float* __restrict__ m2w2,
                         const float* __restrict__ wq,
                         short* __restrict__ w1p1, short* __restrict__ w2p1,
                         short* __restrict__ w1p2, short* __restrict__ w2p2,
                         short* __restrict__ wqp) {
  int idx = blockIdx.x * 256 + threadIdx.x;
  const float* W; short* P; int KS, N, base;
  if (idx < 65536)       { W = m1w1; P = w1p1; KS = 4;  N = 512; base = 0; }
  else if (idx < 131072) { W = m1w2; P = w2p1; KS = 16; N = 128; base = 65536; }
  else if (idx < 196608) { W = m2w1; P = w1p2; KS = 4;  N = 512; base = 131072; }
  else if (idx < 262144) { W = m2w2; P = w2p2; KS = 16; N = 128; base = 196608; }
  else if (idx < 278528) { W = wq;   P = wqp;  KS = 4;  N = 128; base = 262144; }
  else return;
  int i = idx - base;
  int j    = i & 7;
  int lane = (i >> 3) & 63;
  int ks   = (i >> 9) % KS;
  int nt   = i / (KS << 9);
  int k = ks * 32 + ((lane >> 4) << 3) + j;
  int n = nt * 16 + (lane & 15);
  P[i] = f2b(W[k * N + n]);
}

// ---------------------------------------------------------------------------
// Stage B: x_proj(bf16) = LN(x + MLP1(x)). 64 rows/block, h in 4 quarters.
// Transposed GEMMs: C row = output dim, C col = activation row (= ln16).
// LDS 34816 B -> 4 blocks/CU.
// ---------------------------------------------------------------------------
__global__ __launch_bounds__(256, 4)
void k_mlp_ln(const float* __restrict__ X, short* __restrict__ OUTb,
              const short* __restrict__ w1p, const float* __restrict__ b1,
              const short* __restrict__ w2p, const float* __restrict__ b2,
              const float* __restrict__ g, const float* __restrict__ be) {
  __shared__ __align__(16) short xb[64 * 136];
  __shared__ __align__(16) short hb[64 * 136];
  const int tid  = threadIdx.x;
  const int lane = tid & 63;
  const int wave = tid >> 6;
  const int quad = lane >> 4;
  const int ln16 = lane & 15;
  const long rowbase = (long)blockIdx.x * 64;
  const float* xsrc = X + rowbase * 128;

#pragma unroll
  for (int i = 0; i < 8; ++i) {
    int flat = tid + 256 * i;
    int r  = flat >> 5;
    int c4 = (flat & 31) << 2;
    floatx4 v = *(const floatx4*)(xsrc + r * 128 + c4);
    short4v s;
    s[0] = f2b(v[0]); s[1] = f2b(v[1]); s[2] = f2b(v[2]); s[3] = f2b(v[3]);
    *(short4v*)&xb[r * 136 + c4] = s;
  }
  __syncthreads();

  const int wr = wave * 16;
  floatx4 acc2[8];
#pragma unroll
  for (int i = 0; i < 8; ++i) acc2[i] = (floatx4){0.f, 0.f, 0.f, 0.f};

#pragma unroll 1
  for (int qtr = 0; qtr < 4; ++qtr) {
    for (int nt2 = 0; nt2 < 8; ++nt2) {
      const int ntg = qtr * 8 + nt2;
      floatx4 acc = {0.f, 0.f, 0.f, 0.f};
#pragma unroll
      for (int ks = 0; ks < 4; ++ks) {
        short8 bf = *(const short8*)&xb[(wr + ln16) * 136 + ks * 32 + quad * 8];
        short8 af = *(const short8*)&w1p[((ntg * 4 + ks) * 64 + lane) * 8];
        acc = MFMA_BF16(af, bf, acc);
      }
      floatx4 bias = *(const floatx4*)&b1[ntg * 16 + quad * 4];
      short4v hv;
#pragma unroll
      for (int r = 0; r < 4; ++r) hv[r] = f2b(gelu_fast(acc[r] + bias[r]));
      *(short4v*)&hb[(wr + ln16) * 136 + nt2 * 16 + quad * 4] = hv;
    }
    __syncthreads();
    for (int nt = 0; nt < 8; ++nt) {
      floatx4 a2 = acc2[nt];
#pragma unroll
      for (int ks = 0; ks < 4; ++ks) {
        short8 bf = *(const short8*)&hb[(wr + ln16) * 136 + ks * 32 + quad * 8];
        short8 af = *(const short8*)&w2p[((nt * 16 + qtr * 4 + ks) * 64 + lane) * 8];
        a2 = MFMA_BF16(af, bf, a2);
      }
      acc2[nt] = a2;
    }
    __syncthreads();
  }

  // epilogue: lane holds out[row = wr+ln16][dim = nt*16+quad*4+r]
  const int row = wr + ln16;
  const float* xr = xsrc + row * 128;
  float s1 = 0.f, s2 = 0.f;
#pragma unroll
  for (int nt = 0; nt < 8; ++nt) {
    floatx4 xres = *(const floatx4*)(xr + nt * 16 + quad * 4);
    floatx4 bb   = *(const floatx4*)&b2[nt * 16 + quad * 4];
#pragma unroll
    for (int r = 0; r < 4; ++r) {
      float v = acc2[nt][r] + bb[r] + xres[r];
      acc2[nt][r] = v; s1 += v; s2 += v * v;
    }
  }
  s1 += __shfl_xor(s1, 16); s1 += __shfl_xor(s1, 32);
  s2 += __shfl_xor(s2, 16); s2 += __shfl_xor(s2, 32);
  const float mean = s1 * (1.0f / 128.0f);
  const float rstd = rsqrtf(s2 * (1.0f / 128.0f) - mean * mean + 1e-5f);
  short* orow = OUTb + (rowbase + row) * 128;
#pragma unroll
  for (int nt = 0; nt < 8; ++nt) {
    floatx4 gg = *(const floatx4*)&g[nt * 16 + quad * 4];
    floatx4 bb = *(const floatx4*)&be[nt * 16 + quad * 4];
    short4v o;
#pragma unroll
    for (int r = 0; r < 4; ++r)
      o[r] = f2b((acc2[nt][r] - mean) * rstd * gg[r] + bb[r]);
    *(short4v*)&orow[nt * 16 + quad * 4] = o;
  }
}

// ---------------------------------------------------------------------------
// Stage C: banded attn1 -> buffer. Only t<15 K/V rows matter. 1 block/(b,l).
// ---------------------------------------------------------------------------
__global__ __launch_bounds__(256, 2)
void k_buffer(const short* __restrict__ XPb, const float* __restrict__ router,
              const float* __restrict__ w_r, const float* __restrict__ b_r,
              const float* __restrict__ w_k, const float* __restrict__ b_k,
              const float* __restrict__ w_v, const float* __restrict__ b_v,
              float* __restrict__ BUF) {
  __shared__ float xs[15 * 128];
  __shared__ float rf[10 * 128];
  __shared__ float kp[15 * 128];
  __shared__ float vp[15 * 128];
  __shared__ float rp[10 * 128];
  const int bl = blockIdx.x;
  const int b = bl >> 5, l = bl & 31;
  const int tid = threadIdx.x;

  for (int i = tid; i < 15 * 128; i += 256) {
    int t = i >> 7, c = i & 127;
    xs[i] = b2f(XPb[(((long)b * 1024 + t) * 32 + l) * 128 + c]);
  }
  for (int i = tid; i < 10 * 128; i += 256) rf[i] = router[(long)l * 1280 + i];
  __syncthreads();

  for (int i = tid; i < 40 * 128; i += 256) {
    int t = i >> 7, c = i & 127;
    const float* xr;
    const float* W;
    float acc;
    if (t < 15)      { xr = &xs[t * 128];        W = w_k; acc = b_k[c]; }
    else if (t < 30) { xr = &xs[(t - 15) * 128]; W = w_v; acc = b_v[c]; }
    else             { xr = &rf[(t - 30) * 128]; W = w_r; acc = b_r[c]; }
    float a0 = 0.f, a1 = 0.f, a2 = 0.f, a3 = 0.f;
    for (int d = 0; d < 128; d += 4) {
      a0 += xr[d]     * W[d * 128 + c];
      a1 += xr[d + 1] * W[(d + 1) * 128 + c];
      a2 += xr[d + 2] * W[(d + 2) * 128 + c];
      a3 += xr[d + 3] * W[(d + 3) * 128 + c];
    }
    acc += (a0 + a1) + (a2 + a3);
    if (t < 15)      kp[t * 128 + c] = acc;
    else if (t < 30) vp[(t - 15) * 128 + c] = acc;
    else             rp[(t - 30) * 128 + c] = acc;
  }
  __syncthreads();

  if (tid < 20) {
    const int i = tid >> 1, hd = tid & 1;
    const int jlo = (i - 5 < 0) ? 0 : i - 5;
    const int jhi = i + 5;  // <= 14
    float sc[15];
    float mx = -1e30f;
    for (int j = jlo; j <= jhi; ++j) {
      float s = 0.f;
      for (int d = 0; d < 64; ++d) s += rp[i * 128 + hd * 64 + d] * kp[j * 128 + hd * 64 + d];
      s *= 0.125f;
      s = fminf(fmaxf(s, -10000.0f), 10000.0f);
      sc[j] = s; mx = fmaxf(mx, s);
    }
    float den = 0.f;
    for (int j = jlo; j <= jhi; ++j) { sc[j] = expf(sc[j] - mx); den += sc[j]; }
    const float rden = 1.0f / den;
    for (int d = 0; d < 64; ++d) {
      float o = 0.f;
      for (int j = jlo; j <= jhi; ++j) o += sc[j] * vp[j * 128 + hd * 64 + d];
      BUF[((bl * 2 + hd) * 10 + i) * 64 + d] = o * rden;
    }
  }
}

// ---------------------------------------------------------------------------
// Stage D: q-proj + attn2(10 keys, static/masked) + MLP2 + LN2 + LN3 -> out.
// LDS = xb 17408 + qh 17408 + kv 5120 = 39936 B -> 4 blocks/CU.
// Buffer ping-pong: xb{x_proj -> recv}, qh{q -> h-quarter}.
// ---------------------------------------------------------------------------
__global__ __launch_bounds__(256, 4)
void k_attn_mlp(const short* __restrict__ XPb, const float* __restrict__ BUF,
                float* __restrict__ OUT,
                const short* __restrict__ wqp, const float* __restrict__ bq,
                const short* __restrict__ w1p, const float* __restrict__ b1,
                const short* __restrict__ w2p, const float* __restrict__ b2,
                const float* __restrict__ g2, const float* __restrict__ be2,
                const float* __restrict__ g3, const float* __restrict__ be3) {
  __shared__ __align__(16) short xb[64 * 136];
  __shared__ __align__(16) short qh[64 * 136];
  __shared__ __align__(16) float kv[1280];

  const int tid  = threadIdx.x;
  const int lane = tid & 63;
  const int wave = tid >> 6;
  const int quad = lane >> 4;
  const int ln16 = lane & 15;

  const int bx = blockIdx.x;
  const int bl = bx >> 4;
  const int tt = bx & 15;
  const int b = bl >> 5, l = bl & 31;
  const int t0 = tt * 64;
  const long basef = ((long)(b * 1024 + t0) * 32 + l) * 128;  // row stride 4096

#pragma unroll
  for (int i = 0; i < 4; ++i) {
    int flat = tid + 256 * i;
    int r  = flat >> 4;
    int c8 = (flat & 15) << 3;
    short8 v = *(const short8*)(XPb + basef + (long)r * 4096 + c8);
    *(short8*)&xb[r * 136 + c8] = v;
  }
  for (int i = tid; i < 1280; i += 256) kv[i] = BUF[bl * 1280 + i];
  __syncthreads();

  const int wr = wave * 16;
  // q projection -> qh (bf16, vector writes)
  for (int nt = 0; nt < 8; ++nt) {
    floatx4 acc = {0.f, 0.f, 0.f, 0.f};
#pragma unroll
    for (int ks = 0; ks < 4; ++ks) {
      short8 bf = *(const short8*)&xb[(wr + ln16) * 136 + ks * 32 + quad * 8];
      short8 af = *(const short8*)&wqp[((nt * 4 + ks) * 64 + lane) * 8];
      acc = MFMA_BF16(af, bf, acc);
    }
    floatx4 bb = *(const floatx4*)&bq[nt * 16 + quad * 4];
    short4v qv;
#pragma unroll
    for (int r = 0; r < 4; ++r) qv[r] = f2b(acc[r] + bb[r]);
    *(short4v*)&qh[(wr + ln16) * 136 + nt * 16 + quad * 4] = qv;
  }
  __syncthreads();

  // attention: static full 10-j loops; band (t<10) handled by -inf mask
  if (tid < 128) {
    const int row = tid >> 1, hd = tid & 1;
    const int t = t0 + row;
    const short* qrow = &qh[row * 136 + hd * 64];
    const float* kvh  = &kv[hd * 640];
    float p[10];
#pragma unroll
    for (int j = 0; j < 10; ++j) p[j] = 0.f;
#pragma unroll
    for (int c = 0; c < 8; ++c) {
      short8 qs = *(const short8*)&qrow[c * 8];
      float qf[8];
#pragma unroll
      for (int u = 0; u < 8; ++u) qf[u] = b2f(qs[u]);
#pragma unroll
      for (int j = 0; j < 10; ++j) {
        const float* kp = &kvh[j * 64 + c * 8];
        floatx4 k0 = *(const floatx4*)kp;
        floatx4 k1 = *(const floatx4*)(kp + 4);
        p[j] += qf[0] * k0[0] + qf[1] * k0[1] + qf[2] * k0[2] + qf[3] * k0[3]
              + qf[4] * k1[0] + qf[5] * k1[1] + qf[6] * k1[2] + qf[7] * k1[3];
      }
    }
    const bool full = (t >= 10);
    const int jlo = t - 5, jhi = t + 5;
    float mx = -1e30f;
#pragma unroll
    for (int j = 0; j < 10; ++j) {
      float s = fminf(fmaxf(p[j] * 0.125f, -10000.0f), 10000.0f);
      s = (full || (j >= jlo && j <= jhi)) ? s : -1e30f;
      p[j] = s; mx = fmaxf(mx, s);
    }
    float den = 0.f;
#pragma unroll
    for (int j = 0; j < 10; ++j) { p[j] = __expf(p[j] - mx); den += p[j]; }
    const float rden = 1.0f / den;
#pragma unroll
    for (int j = 0; j < 10; ++j) p[j] *= rden;
#pragma unroll
    for (int c = 0; c < 16; ++c) {
      floatx4 o = {0.f, 0.f, 0.f, 0.f};
#pragma unroll
      for (int j = 0; j < 10; ++j) {
        floatx4 vv = *(const floatx4*)&kvh[j * 64 + c * 4];
        o += p[j] * vv;
      }
      short4v s;
#pragma unroll
      for (int r = 0; r < 4; ++r) s[r] = f2b(o[r]);
      *(short4v*)&xb[row * 136 + hd * 64 + c * 4] = s;
    }
  }
  __syncthreads();

  // MLP2 on recv (xb), h quarters through qh
  floatx4 acc2[8];
#pragma unroll
  for (int i = 0; i < 8; ++i) acc2[i] = (floatx4){0.f, 0.f, 0.f, 0.f};

#pragma unroll 1
  for (int qtr = 0; qtr < 4; ++qtr) {
    for (int nt2 = 0; nt2 < 8; ++nt2) {
      const int ntg = qtr * 8 + nt2;
      floatx4 acc = {0.f, 0.f, 0.f, 0.f};
#pragma unroll
      for (int ks = 0; ks < 4; ++ks) {
        short8 bf = *(const short8*)&xb[(wr + ln16) * 136 + ks * 32 + quad * 8];
        short8 af = *(const short8*)&w1p[((ntg * 4 + ks) * 64 + lane) * 8];
        acc = MFMA_BF16(af, bf, acc);
      }
      floatx4 bias = *(const floatx4*)&b1[ntg * 16 + quad * 4];
      short4v hv;
#pragma unroll
      for (int r = 0; r < 4; ++r) hv[r] = f2b(gelu_fast(acc[r] + bias[r]));
      *(short4v*)&qh[(wr + ln16) * 136 + nt2 * 16 + quad * 4] = hv;
    }
    __syncthreads();
    for (int nt = 0; nt < 8; ++nt) {
      floatx4 a2 = acc2[nt];
#pragma unroll
      for (int ks = 0; ks < 4; ++ks) {
        short8 bf = *(const short8*)&qh[(wr + ln16) * 136 + ks * 32 + quad * 8];
        short8 af = *(const short8*)&w2p[((nt * 16 + qtr * 4 + ks) * 64 + lane) * 8];
        a2 = MFMA_BF16(af, bf, a2);
      }
      acc2[nt] = a2;
    }
    __syncthreads();
  }

  // epilogue: + x_proj residual (bf16 vector re-read), LN2 then LN3
  const int row = wr + ln16;
  const short* xrb = XPb + basef + (long)row * 4096;
  float s1 = 0.f, s2 = 0.f;
#pragma unroll
  for (int nt = 0; nt < 8; ++nt) {
    short4v xs4 = *(const short4v*)&xrb[nt * 16 + quad * 4];
    floatx4 bb  = *(const floatx4*)&b2[nt * 16 + quad * 4];
#pragma unroll
    for (int r = 0; r < 4; ++r) {
      float v = acc2[nt][r] + bb[r] + b2f(xs4[r]);
      acc2[nt][r] = v; s1 += v; s2 += v * v;
    }
  }
  s1 += __shfl_xor(s1, 16); s1 += __shfl_xor(s1, 32);
  s2 += __shfl_xor(s2, 16); s2 += __shfl_xor(s2, 32);
  const float mean1 = s1 * (1.0f / 128.0f);
  const float rstd1 = rsqrtf(s2 * (1.0f / 128.0f) - mean1 * mean1 + 1e-5f);

  s1 = 0.f; s2 = 0.f;
#pragma unroll
  for (int nt = 0; nt < 8; ++nt) {
    floatx4 gg = *(const floatx4*)&g2[nt * 16 + quad * 4];
    floatx4 bb = *(const floatx4*)&be2[nt * 16 + quad * 4];
#pragma unroll
    for (int r = 0; r < 4; ++r) {
      float z = (acc2[nt][r] - mean1) * rstd1 * gg[r] + bb[r];
      s1 += z; s2 += z * z;
    }
  }
  s1 += __shfl_xor(s1, 16); s1 += __shfl_xor(s1, 32);
  s2 += __shfl_xor(s2, 16); s2 += __shfl_xor(s2, 32);
  const float mean2 = s1 * (1.0f / 128.0f);
  const float rstd2 = rsqrtf(s2 * (1.0f / 128.0f) - mean2 * mean2 + 1e-5f);

  float* orow = OUT + basef + (long)row * 4096;
#pragma unroll
  for (int nt = 0; nt < 8; ++nt) {
    floatx4 gg2 = *(const floatx4*)&g2[nt * 16 + quad * 4];
    floatx4 bb2 = *(const floatx4*)&be2[nt * 16 + quad * 4];
    floatx4 gg3 = *(const floatx4*)&g3[nt * 16 + quad * 4];
    floatx4 bb3 = *(const floatx4*)&be3[nt * 16 + quad * 4];
    floatx4 o4;
#pragma unroll
    for (int r = 0; r < 4; ++r) {
      float z = (acc2[nt][r] - mean1) * rstd1 * gg2[r] + bb2[r];
      o4[r] = (z - mean2) * rstd2 * gg3[r] + bb3[r];
    }
    *(floatx4*)&orow[nt * 16 + quad * 4] = o4;
  }
}

// ---------------------------------------------------------------------------
extern "C" void kernel_launch(void* const* d_in, const int* in_sizes, int n_in,
                              void* d_out, int out_size, void* d_ws, size_t ws_size,
                              hipStream_t stream) {
  const float* x        = (const float*)d_in[0];
  const float* router   = (const float*)d_in[1];
  const float* w_router = (const float*)d_in[2];
  const float* b_router = (const float*)d_in[3];
  const float* w_k  = (const float*)d_in[4];
  const float* b_k  = (const float*)d_in[5];
  const float* w_v  = (const float*)d_in[6];
  const float* b_v  = (const float*)d_in[7];
  const float* w_q  = (const float*)d_in[8];
  const float* b_q  = (const float*)d_in[9];
  const float* m1w1 = (const float*)d_in[10];
  const float* m1b1 = (const float*)d_in[11];
  const float* m1w2 = (const float*)d_in[12];
  const float* m1b2 = (const float*)d_in[13];
  const float* m2w1 = (const float*)d_in[14];
  const float* m2b1 = (const float*)d_in[15];
  const float* m2w2 = (const float*)d_in[16];
  const float* m2b2 = (const float*)d_in[17];
  const float* g1  = (const float*)d_in[18];
  const float* be1 = (const float*)d_in[19];
  const float* g2  = (const float*)d_in[20];
  const float* be2 = (const float*)d_in[21];
  const float* g3  = (const float*)d_in[22];
  const float* be3 = (const float*)d_in[23];
  float* out = (float*)d_out;

  char* ws = (char*)d_ws;
  short* XPb = (short*)ws;                      // x_proj bf16: 32 MiB
  float* BUF = (float*)(ws + 33554432);         // 640 KiB
  short* w1p1 = (short*)(ws + 34209792);
  short* w2p1 = w1p1 + 65536;
  short* w1p2 = w2p1 + 65536;
  short* w2p2 = w1p2 + 65536;
  short* wqp  = w2p2 + 65536;

  pack_all<<<1088, 256, 0, stream>>>(m1w1, m1w2, m2w1, m2w2, w_q,
                                     w1p1, w2p1, w1p2, w2p2, wqp);
  k_mlp_ln<<<2048, 256, 0, stream>>>(x, XPb, w1p1, m1b1, w2p1, m1b2, g1, be1);
  k_buffer<<<128, 256, 0, stream>>>(XPb, router, w_router, b_router,
                                    w_k, b_k, w_v, b_v, BUF);
  k_attn_mlp<<<2048, 256, 0, stream>>>(XPb, BUF, out, wqp, b_q,
                                       w1p2, m2b1, w2p2, m2b2,
                                       g2, be2, g3, be3);
}

// Round 4
// 475.953 us; speedup vs baseline: 1.6153x; 1.4092x over previous
//
#include <hip/hip_runtime.h>
#include <math.h>

// ---------------------------------------------------------------------------
// QuadraLayer fused, bf16-MFMA path, round 4.
// Change vs r3: k_buffer rewritten — MFMA projections (w_k/w_v/w_r packed as
// fragments) + fully parallel banded attention (220-thread score phase,
// 1280-element output phase). r3's k_buffer was a 207us serialization bug
// (20 serial dot-128s/thread, 20-of-256-thread attention).
// ---------------------------------------------------------------------------

typedef short short8 __attribute__((ext_vector_type(8)));
typedef short short4v __attribute__((ext_vector_type(4)));
typedef float floatx4 __attribute__((ext_vector_type(4)));

#define MFMA_BF16(a, b, c) __builtin_amdgcn_mfma_f32_16x16x32_bf16((a), (b), (c), 0, 0, 0)

__device__ __forceinline__ short f2b(float f) {
  unsigned u = __builtin_bit_cast(unsigned, f);
  u += 0x7FFFu + ((u >> 16) & 1u);
  return (short)(u >> 16);
}
__device__ __forceinline__ float b2f(short s) {
  unsigned u = ((unsigned)(unsigned short)s) << 16;
  return __builtin_bit_cast(float, u);
}
// gelu(v) = 0.5 v (1+erf(v/sqrt2)); erf via A&S 7.1.26 (|eps|<=1.5e-7)
__device__ __forceinline__ float gelu_fast(float v) {
  float z  = v * 0.70710678118654752f;
  float az = fabsf(z);
  float t  = __builtin_amdgcn_rcpf(1.0f + 0.3275911f * az);
  float poly = ((((1.061405429f * t - 1.453152027f) * t + 1.421413741f) * t
                 - 0.284496736f) * t + 0.254829592f) * t;
  float e = 1.0f - poly * __expf(-az * az);
  float erfv = copysignf(e, z);
  return 0.5f * v * (1.0f + erfv);
}

// ---------------------------------------------------------------------------
// Pack all weights into bf16 MFMA fragments.
// lane -> (free dim = lane&15, k = (lane>>4)*8+j); P[((nt*KS+ks)*64+lane)*8+j]
// ---------------------------------------------------------------------------
__global__ void pack_all(const float* __restrict__ m1w1, const float* __restrict__ m1w2,
                         const float* __restrict__ m2w1, const float* __restrict__ m2w2,
                         const float* __restrict__ wq,
                         const float* __restrict__ wk, const float* __restrict__ wv,
                         const float* __restrict__ wr,
                         short* __restrict__ w1p1, short* __restrict__ w2p1,
                         short* __restrict__ w1p2, short* __restrict__ w2p2,
                         short* __restrict__ wqp, short* __restrict__ wkp,
                         short* __restrict__ wvp, short* __restrict__ wrp) {
  int idx = blockIdx.x * 256 + threadIdx.x;
  const float* W; short* P; int KS, N, base;
  if (idx < 65536)       { W = m1w1; P = w1p1; KS = 4;  N = 512; base = 0; }
  else if (idx < 131072) { W = m1w2; P = w2p1; KS = 16; N = 128; base = 65536; }
  else if (idx < 196608) { W = m2w1; P = w1p2; KS = 4;  N = 512; base = 131072; }
  else if (idx < 262144) { W = m2w2; P = w2p2; KS = 16; N = 128; base = 196608; }
  else if (idx < 278528) { W = wq;   P = wqp;  KS = 4;  N = 128; base = 262144; }
  else if (idx < 294912) { W = wk;   P = wkp;  KS = 4;  N = 128; base = 278528; }
  else if (idx < 311296) { W = wv;   P = wvp;  KS = 4;  N = 128; base = 294912; }
  else if (idx < 327680) { W = wr;   P = wrp;  KS = 4;  N = 128; base = 311296; }
  else return;
  int i = idx - base;
  int j    = i & 7;
  int lane = (i >> 3) & 63;
  int ks   = (i >> 9) % KS;
  int nt   = i / (KS << 9);
  int k = ks * 32 + ((lane >> 4) << 3) + j;
  int n = nt * 16 + (lane & 15);
  P[i] = f2b(W[k * N + n]);
}

// ---------------------------------------------------------------------------
// Stage B: x_proj(bf16) = LN(x + MLP1(x)). 64 rows/block, h in 4 quarters.
// Transposed GEMMs: weights = A operand, activations = B operand.
// ---------------------------------------------------------------------------
__global__ __launch_bounds__(256, 4)
void k_mlp_ln(const float* __restrict__ X, short* __restrict__ OUTb,
              const short* __restrict__ w1p, const float* __restrict__ b1,
              const short* __restrict__ w2p, const float* __restrict__ b2,
              const float* __restrict__ g, const float* __restrict__ be) {
  __shared__ __align__(16) short xb[64 * 136];
  __shared__ __align__(16) short hb[64 * 136];
  const int tid  = threadIdx.x;
  const int lane = tid & 63;
  const int wave = tid >> 6;
  const int quad = lane >> 4;
  const int ln16 = lane & 15;
  const long rowbase = (long)blockIdx.x * 64;
  const float* xsrc = X + rowbase * 128;

#pragma unroll
  for (int i = 0; i < 8; ++i) {
    int flat = tid + 256 * i;
    int r  = flat >> 5;
    int c4 = (flat & 31) << 2;
    floatx4 v = *(const floatx4*)(xsrc + r * 128 + c4);
    short4v s;
    s[0] = f2b(v[0]); s[1] = f2b(v[1]); s[2] = f2b(v[2]); s[3] = f2b(v[3]);
    *(short4v*)&xb[r * 136 + c4] = s;
  }
  __syncthreads();

  const int wr = wave * 16;
  floatx4 acc2[8];
#pragma unroll
  for (int i = 0; i < 8; ++i) acc2[i] = (floatx4){0.f, 0.f, 0.f, 0.f};

#pragma unroll 1
  for (int qtr = 0; qtr < 4; ++qtr) {
    for (int nt2 = 0; nt2 < 8; ++nt2) {
      const int ntg = qtr * 8 + nt2;
      floatx4 acc = {0.f, 0.f, 0.f, 0.f};
#pragma unroll
      for (int ks = 0; ks < 4; ++ks) {
        short8 bf = *(const short8*)&xb[(wr + ln16) * 136 + ks * 32 + quad * 8];
        short8 af = *(const short8*)&w1p[((ntg * 4 + ks) * 64 + lane) * 8];
        acc = MFMA_BF16(af, bf, acc);
      }
      floatx4 bias = *(const floatx4*)&b1[ntg * 16 + quad * 4];
      short4v hv;
#pragma unroll
      for (int r = 0; r < 4; ++r) hv[r] = f2b(gelu_fast(acc[r] + bias[r]));
      *(short4v*)&hb[(wr + ln16) * 136 + nt2 * 16 + quad * 4] = hv;
    }
    __syncthreads();
    for (int nt = 0; nt < 8; ++nt) {
      floatx4 a2 = acc2[nt];
#pragma unroll
      for (int ks = 0; ks < 4; ++ks) {
        short8 bf = *(const short8*)&hb[(wr + ln16) * 136 + ks * 32 + quad * 8];
        short8 af = *(const short8*)&w2p[((nt * 16 + qtr * 4 + ks) * 64 + lane) * 8];
        a2 = MFMA_BF16(af, bf, a2);
      }
      acc2[nt] = a2;
    }
    __syncthreads();
  }

  const int row = wr + ln16;
  const float* xr = xsrc + row * 128;
  float s1 = 0.f, s2 = 0.f;
#pragma unroll
  for (int nt = 0; nt < 8; ++nt) {
    floatx4 xres = *(const floatx4*)(xr + nt * 16 + quad * 4);
    floatx4 bb   = *(const floatx4*)&b2[nt * 16 + quad * 4];
#pragma unroll
    for (int r = 0; r < 4; ++r) {
      float v = acc2[nt][r] + bb[r] + xres[r];
      acc2[nt][r] = v; s1 += v; s2 += v * v;
    }
  }
  s1 += __shfl_xor(s1, 16); s1 += __shfl_xor(s1, 32);
  s2 += __shfl_xor(s2, 16); s2 += __shfl_xor(s2, 32);
  const float mean = s1 * (1.0f / 128.0f);
  const float rstd = rsqrtf(s2 * (1.0f / 128.0f) - mean * mean + 1e-5f);
  short* orow = OUTb + (rowbase + row) * 128;
#pragma unroll
  for (int nt = 0; nt < 8; ++nt) {
    floatx4 gg = *(const floatx4*)&g[nt * 16 + quad * 4];
    floatx4 bb = *(const floatx4*)&be[nt * 16 + quad * 4];
    short4v o;
#pragma unroll
    for (int r = 0; r < 4; ++r)
      o[r] = f2b((acc2[nt][r] - mean) * rstd * gg[r] + bb[r]);
    *(short4v*)&orow[nt * 16 + quad * 4] = o;
  }
}

// ---------------------------------------------------------------------------
// Stage C: K/V (t<15) + router projections via MFMA, then banded attn1.
// One block per (b,l). LDS 23 KB.
// ---------------------------------------------------------------------------
__global__ __launch_bounds__(256, 4)
void k_buffer(const short* __restrict__ XPb, const float* __restrict__ router,
              const short* __restrict__ wkp, const float* __restrict__ b_k,
              const short* __restrict__ wvp, const float* __restrict__ b_v,
              const short* __restrict__ wrp, const float* __restrict__ b_r,
              float* __restrict__ BUF) {
  __shared__ __align__(16) short ab[32 * 136];  // rows 0-14: x(t), rows 16-25: router
  __shared__ __align__(16) short kp[16 * 136];
  __shared__ __align__(16) short vp[16 * 136];
  __shared__ __align__(16) short rp[16 * 136];
  __shared__ float sc[20 * 16];
  const int tid  = threadIdx.x;
  const int lane = tid & 63;
  const int wave = tid >> 6;
  const int quad = lane >> 4;
  const int ln16 = lane & 15;
  const int bl = blockIdx.x;
  const int b = bl >> 5, l = bl & 31;

  // stage x rows t=0..14 (bf16 direct), 240 short8 chunks
  if (tid < 240) {
    int r = tid >> 4, c8 = (tid & 15) << 3;
    short8 v = *(const short8*)(XPb + (((long)b * 1024 + r) * 32 + l) * 128 + c8);
    *(short8*)&ab[r * 136 + c8] = v;
  }
  // stage router rows 0..9 (fp32 -> bf16), 320 float4 chunks
  for (int i = tid; i < 320; i += 256) {
    int r = i >> 5, c4 = (i & 31) << 2;
    floatx4 v = *(const floatx4*)(router + (long)l * 1280 + r * 128 + c4);
    short4v s;
    s[0] = f2b(v[0]); s[1] = f2b(v[1]); s[2] = f2b(v[2]); s[3] = f2b(v[3]);
    *(short4v*)&ab[(16 + r) * 136 + c4] = s;
  }
  __syncthreads();

  // 24 tile-columns: m = idx>>3 (0:K 1:V 2:R), nt = idx&7
  for (int idx = wave; idx < 24; idx += 4) {
    const int m = idx >> 3, nt = idx & 7;
    const short* wp   = (m == 0) ? wkp : (m == 1) ? wvp : wrp;
    const float* bias = (m == 0) ? b_k : (m == 1) ? b_v : b_r;
    const int abase = (m == 2) ? 16 * 136 : 0;
    floatx4 acc = {0.f, 0.f, 0.f, 0.f};
#pragma unroll
    for (int ks = 0; ks < 4; ++ks) {
      short8 bf = *(const short8*)&ab[abase + ln16 * 136 + ks * 32 + quad * 8];
      short8 af = *(const short8*)&wp[((nt * 4 + ks) * 64 + lane) * 8];
      acc = MFMA_BF16(af, bf, acc);
    }
    floatx4 bb = *(const floatx4*)&bias[nt * 16 + quad * 4];
    short* dst = (m == 0) ? kp : (m == 1) ? vp : rp;
    short4v o;
#pragma unroll
    for (int r = 0; r < 4; ++r) o[r] = f2b(acc[r] + bb[r]);
    *(short4v*)&dst[ln16 * 136 + nt * 16 + quad * 4] = o;
  }
  __syncthreads();

  // phase 1: 220 score dots (pair = (i,hd), jrel in [0,11))
  for (int t = tid; t < 220; t += 256) {
    int pair = t / 11, jrel = t - pair * 11;
    int i = pair >> 1, hd = pair & 1;
    int j = i - 5 + jrel;
    float s;
    if (j < 0) s = -1e30f;
    else {
      float a0 = 0.f, a1 = 0.f;
      for (int d = 0; d < 64; d += 2) {
        a0 += b2f(rp[i * 136 + hd * 64 + d])     * b2f(kp[j * 136 + hd * 64 + d]);
        a1 += b2f(rp[i * 136 + hd * 64 + d + 1]) * b2f(kp[j * 136 + hd * 64 + d + 1]);
      }
      s = fminf(fmaxf((a0 + a1) * 0.125f, -10000.0f), 10000.0f);
    }
    sc[pair * 16 + jrel] = s;
  }
  __syncthreads();
  // phase 2: softmax over 11 per pair
  if (tid < 20) {
    float mx = -1e30f;
    for (int jr = 0; jr < 11; ++jr) mx = fmaxf(mx, sc[tid * 16 + jr]);
    float den = 0.f, e[11];
    for (int jr = 0; jr < 11; ++jr) { e[jr] = __expf(sc[tid * 16 + jr] - mx); den += e[jr]; }
    float rden = 1.0f / den;
    for (int jr = 0; jr < 11; ++jr) sc[tid * 16 + jr] = e[jr] * rden;
  }
  __syncthreads();
  // phase 3: 1280 output elements
  for (int e = tid; e < 1280; e += 256) {
    int pair = e >> 6, d = e & 63;
    int i = pair >> 1, hd = pair & 1;
    float o = 0.f;
#pragma unroll
    for (int jr = 0; jr < 11; ++jr) {
      int j = i - 5 + jr;
      int jc = (j < 0) ? 0 : j;                 // p==0 for invalid j
      o += sc[pair * 16 + jr] * b2f(vp[jc * 136 + hd * 64 + d]);
    }
    BUF[((bl * 2 + hd) * 10 + i) * 64 + d] = o;
  }
}

// ---------------------------------------------------------------------------
// Stage D: q-proj + attn2(10 keys, static/masked) + MLP2 + LN2 + LN3 -> out.
// ---------------------------------------------------------------------------
__global__ __launch_bounds__(256, 4)
void k_attn_mlp(const short* __restrict__ XPb, const float* __restrict__ BUF,
                float* __restrict__ OUT,
                const short* __restrict__ wqp, const float* __restrict__ bq,
                const short* __restrict__ w1p, const float* __restrict__ b1,
                const short* __restrict__ w2p, const float* __restrict__ b2,
                const float* __restrict__ g2, const float* __restrict__ be2,
                const float* __restrict__ g3, const float* __restrict__ be3) {
  __shared__ __align__(16) short xb[64 * 136];
  __shared__ __align__(16) short qh[64 * 136];
  __shared__ __align__(16) float kv[1280];

  const int tid  = threadIdx.x;
  const int lane = tid & 63;
  const int wave = tid >> 6;
  const int quad = lane >> 4;
  const int ln16 = lane & 15;

  const int bx = blockIdx.x;
  const int bl = bx >> 4;
  const int tt = bx & 15;
  const int b = bl >> 5, l = bl & 31;
  const int t0 = tt * 64;
  const long basef = ((long)(b * 1024 + t0) * 32 + l) * 128;

#pragma unroll
  for (int i = 0; i < 4; ++i) {
    int flat = tid + 256 * i;
    int r  = flat >> 4;
    int c8 = (flat & 15) << 3;
    short8 v = *(const short8*)(XPb + basef + (long)r * 4096 + c8);
    *(short8*)&xb[r * 136 + c8] = v;
  }
  for (int i = tid; i < 1280; i += 256) kv[i] = BUF[bl * 1280 + i];
  __syncthreads();

  const int wr = wave * 16;
  for (int nt = 0; nt < 8; ++nt) {
    floatx4 acc = {0.f, 0.f, 0.f, 0.f};
#pragma unroll
    for (int ks = 0; ks < 4; ++ks) {
      short8 bf = *(const short8*)&xb[(wr + ln16) * 136 + ks * 32 + quad * 8];
      short8 af = *(const short8*)&wqp[((nt * 4 + ks) * 64 + lane) * 8];
      acc = MFMA_BF16(af, bf, acc);
    }
    floatx4 bb = *(const floatx4*)&bq[nt * 16 + quad * 4];
    short4v qv;
#pragma unroll
    for (int r = 0; r < 4; ++r) qv[r] = f2b(acc[r] + bb[r]);
    *(short4v*)&qh[(wr + ln16) * 136 + nt * 16 + quad * 4] = qv;
  }
  __syncthreads();

  if (tid < 128) {
    const int row = tid >> 1, hd = tid & 1;
    const int t = t0 + row;
    const short* qrow = &qh[row * 136 + hd * 64];
    const float* kvh  = &kv[hd * 640];
    float p[10];
#pragma unroll
    for (int j = 0; j < 10; ++j) p[j] = 0.f;
#pragma unroll
    for (int c = 0; c < 8; ++c) {
      short8 qs = *(const short8*)&qrow[c * 8];
      float qf[8];
#pragma unroll
      for (int u = 0; u < 8; ++u) qf[u] = b2f(qs[u]);
#pragma unroll
      for (int j = 0; j < 10; ++j) {
        const float* kp = &kvh[j * 64 + c * 8];
        floatx4 k0 = *(const floatx4*)kp;
        floatx4 k1 = *(const floatx4*)(kp + 4);
        p[j] += qf[0] * k0[0] + qf[1] * k0[1] + qf[2] * k0[2] + qf[3] * k0[3]
              + qf[4] * k1[0] + qf[5] * k1[1] + qf[6] * k1[2] + qf[7] * k1[3];
      }
    }
    const bool full = (t >= 10);
    const int jlo = t - 5, jhi = t + 5;
    float mx = -1e30f;
#pragma unroll
    for (int j = 0; j < 10; ++j) {
      float s = fminf(fmaxf(p[j] * 0.125f, -10000.0f), 10000.0f);
      s = (full || (j >= jlo && j <= jhi)) ? s : -1e30f;
      p[j] = s; mx = fmaxf(mx, s);
    }
    float den = 0.f;
#pragma unroll
    for (int j = 0; j < 10; ++j) { p[j] = __expf(p[j] - mx); den += p[j]; }
    const float rden = 1.0f / den;
#pragma unroll
    for (int j = 0; j < 10; ++j) p[j] *= rden;
#pragma unroll
    for (int c = 0; c < 16; ++c) {
      floatx4 o = {0.f, 0.f, 0.f, 0.f};
#pragma unroll
      for (int j = 0; j < 10; ++j) {
        floatx4 vv = *(const floatx4*)&kvh[j * 64 + c * 4];
        o += p[j] * vv;
      }
      short4v s;
#pragma unroll
      for (int r = 0; r < 4; ++r) s[r] = f2b(o[r]);
      *(short4v*)&xb[row * 136 + hd * 64 + c * 4] = s;
    }
  }
  __syncthreads();

  floatx4 acc2[8];
#pragma unroll
  for (int i = 0; i < 8; ++i) acc2[i] = (floatx4){0.f, 0.f, 0.f, 0.f};

#pragma unroll 1
  for (int qtr = 0; qtr < 4; ++qtr) {
    for (int nt2 = 0; nt2 < 8; ++nt2) {
      const int ntg = qtr * 8 + nt2;
      floatx4 acc = {0.f, 0.f, 0.f, 0.f};
#pragma unroll
      for (int ks = 0; ks < 4; ++ks) {
        short8 bf = *(const short8*)&xb[(wr + ln16) * 136 + ks * 32 + quad * 8];
        short8 af = *(const short8*)&w1p[((ntg * 4 + ks) * 64 + lane) * 8];
        acc = MFMA_BF16(af, bf, acc);
      }
      floatx4 bias = *(const floatx4*)&b1[ntg * 16 + quad * 4];
      short4v hv;
#pragma unroll
      for (int r = 0; r < 4; ++r) hv[r] = f2b(gelu_fast(acc[r] + bias[r]));
      *(short4v*)&qh[(wr + ln16) * 136 + nt2 * 16 + quad * 4] = hv;
    }
    __syncthreads();
    for (int nt = 0; nt < 8; ++nt) {
      floatx4 a2 = acc2[nt];
#pragma unroll
      for (int ks = 0; ks < 4; ++ks) {
        short8 bf = *(const short8*)&qh[(wr + ln16) * 136 + ks * 32 + quad * 8];
        short8 af = *(const short8*)&w2p[((nt * 16 + qtr * 4 + ks) * 64 + lane) * 8];
        a2 = MFMA_BF16(af, bf, a2);
      }
      acc2[nt] = a2;
    }
    __syncthreads();
  }

  const int row = wr + ln16;
  const short* xrb = XPb + basef + (long)row * 4096;
  float s1 = 0.f, s2 = 0.f;
#pragma unroll
  for (int nt = 0; nt < 8; ++nt) {
    short4v xs4 = *(const short4v*)&xrb[nt * 16 + quad * 4];
    floatx4 bb  = *(const floatx4*)&b2[nt * 16 + quad * 4];
#pragma unroll
    for (int r = 0; r < 4; ++r) {
      float v = acc2[nt][r] + bb[r] + b2f(xs4[r]);
      acc2[nt][r] = v; s1 += v; s2 += v * v;
    }
  }
  s1 += __shfl_xor(s1, 16); s1 += __shfl_xor(s1, 32);
  s2 += __shfl_xor(s2, 16); s2 += __shfl_xor(s2, 32);
  const float mean1 = s1 * (1.0f / 128.0f);
  const float rstd1 = rsqrtf(s2 * (1.0f / 128.0f) - mean1 * mean1 + 1e-5f);

  s1 = 0.f; s2 = 0.f;
#pragma unroll
  for (int nt = 0; nt < 8; ++nt) {
    floatx4 gg = *(const floatx4*)&g2[nt * 16 + quad * 4];
    floatx4 bb = *(const floatx4*)&be2[nt * 16 + quad * 4];
#pragma unroll
    for (int r = 0; r < 4; ++r) {
      float z = (acc2[nt][r] - mean1) * rstd1 * gg[r] + bb[r];
      s1 += z; s2 += z * z;
    }
  }
  s1 += __shfl_xor(s1, 16); s1 += __shfl_xor(s1, 32);
  s2 += __shfl_xor(s2, 16); s2 += __shfl_xor(s2, 32);
  const float mean2 = s1 * (1.0f / 128.0f);
  const float rstd2 = rsqrtf(s2 * (1.0f / 128.0f) - mean2 * mean2 + 1e-5f);

  float* orow = OUT + basef + (long)row * 4096;
#pragma unroll
  for (int nt = 0; nt < 8; ++nt) {
    floatx4 gg2 = *(const floatx4*)&g2[nt * 16 + quad * 4];
    floatx4 bb2 = *(const floatx4*)&be2[nt * 16 + quad * 4];
    floatx4 gg3 = *(const floatx4*)&g3[nt * 16 + quad * 4];
    floatx4 bb3 = *(const floatx4*)&be3[nt * 16 + quad * 4];
    floatx4 o4;
#pragma unroll
    for (int r = 0; r < 4; ++r) {
      float z = (acc2[nt][r] - mean1) * rstd1 * gg2[r] + bb2[r];
      o4[r] = (z - mean2) * rstd2 * gg3[r] + bb3[r];
    }
    *(floatx4*)&orow[nt * 16 + quad * 4] = o4;
  }
}

// ---------------------------------------------------------------------------
extern "C" void kernel_launch(void* const* d_in, const int* in_sizes, int n_in,
                              void* d_out, int out_size, void* d_ws, size_t ws_size,
                              hipStream_t stream) {
  const float* x        = (const float*)d_in[0];
  const float* router   = (const float*)d_in[1];
  const float* w_router = (const float*)d_in[2];
  const float* b_router = (const float*)d_in[3];
  const float* w_k  = (const float*)d_in[4];
  const float* b_k  = (const float*)d_in[5];
  const float* w_v  = (const float*)d_in[6];
  const float* b_v  = (const float*)d_in[7];
  const float* w_q  = (const float*)d_in[8];
  const float* b_q  = (const float*)d_in[9];
  const float* m1w1 = (const float*)d_in[10];
  const float* m1b1 = (const float*)d_in[11];
  const float* m1w2 = (const float*)d_in[12];
  const float* m1b2 = (const float*)d_in[13];
  const float* m2w1 = (const float*)d_in[14];
  const float* m2b1 = (const float*)d_in[15];
  const float* m2w2 = (const float*)d_in[16];
  const float* m2b2 = (const float*)d_in[17];
  const float* g1  = (const float*)d_in[18];
  const float* be1 = (const float*)d_in[19];
  const float* g2  = (const float*)d_in[20];
  const float* be2 = (const float*)d_in[21];
  const float* g3  = (const float*)d_in[22];
  const float* be3 = (const float*)d_in[23];
  float* out = (float*)d_out;

  char* ws = (char*)d_ws;
  short* XPb = (short*)ws;                      // x_proj bf16: 32 MiB
  float* BUF = (float*)(ws + 33554432);         // 640 KiB
  short* w1p1 = (short*)(ws + 34209792);
  short* w2p1 = w1p1 + 65536;
  short* w1p2 = w2p1 + 65536;
  short* w2p2 = w1p2 + 65536;
  short* wqp  = w2p2 + 65536;
  short* wkp  = wqp + 16384;
  short* wvp  = wkp + 16384;
  short* wrp  = wvp + 16384;

  pack_all<<<1280, 256, 0, stream>>>(m1w1, m1w2, m2w1, m2w2, w_q, w_k, w_v, w_router,
                                     w1p1, w2p1, w1p2, w2p2, wqp, wkp, wvp, wrp);
  k_mlp_ln<<<2048, 256, 0, stream>>>(x, XPb, w1p1, m1b1, w2p1, m1b2, g1, be1);
  k_buffer<<<128, 256, 0, stream>>>(XPb, router, wkp, b_k, wvp, b_v, wrp, b_router, BUF);
  k_attn_mlp<<<2048, 256, 0, stream>>>(XPb, BUF, out, wqp, b_q,
                                       w1p2, m2b1, w2p2, m2b2,
                                       g2, be2, g3, be3);
}